// Round 1
// baseline (1940.353 us; speedup 1.0000x reference)
//
#include <hip/hip_runtime.h>
#include <hip/hip_bf16.h>
#include <math.h>

#define NN 50000
#define NE 400000
#define NM 3
#define IND 128
#define OUTD 64
#define NH 4
#define HO 256          // NH*OUTD
#define EPSBN 1e-5f
#define SLOPE 0.2f
#define NTOT (NE + NN)  // edges + self loops

// ---------- helpers: monotonic float<->uint for atomicMax on floats ----------
__device__ __forceinline__ unsigned fkey(float f) {
    unsigned u = __float_as_uint(f);
    return (u & 0x80000000u) ? ~u : (u | 0x80000000u);
}
__device__ __forceinline__ float fkey_inv(unsigned k) {
    unsigned u = (k & 0x80000000u) ? (k ^ 0x80000000u) : ~k;
    return __uint_as_float(u);
}

// ---------- init ----------
__global__ __launch_bounds__(256) void k_init_zall(float* __restrict__ zall) {
    size_t i = (size_t)blockIdx.x * blockDim.x + threadIdx.x;
    size_t tot = (size_t)NN * 192;
    if (i < tot) zall[i] = 0.f;
}

__global__ __launch_bounds__(256) void k_init_m(unsigned* __restrict__ mxu,
                                                float* __restrict__ denom,
                                                int* __restrict__ deg,
                                                float* __restrict__ asum,
                                                float* __restrict__ scal) {
    int i = blockIdx.x * blockDim.x + threadIdx.x;
    if (i < NN * 4) { mxu[i] = 0u; denom[i] = 0.f; }
    if (i < NN) { deg[i] = 0; asum[i] = 0.f; }
    if (i < 16) scal[i] = 0.f;
}

// ---------- BatchNorm over log1p(edge_attr) ----------
__global__ __launch_bounds__(256) void k_bn_reduce(const float* __restrict__ ea,
                                                   float* __restrict__ scal) {
    int i = blockIdx.x * blockDim.x + threadIdx.x;
    int stride = gridDim.x * blockDim.x;
    float s1 = 0.f, s2 = 0.f;
    for (int e = i; e < NE; e += stride) {
        float v = log1pf(ea[e]);
        s1 += v; s2 += v * v;
    }
    #pragma unroll
    for (int o = 32; o > 0; o >>= 1) {
        s1 += __shfl_down(s1, o);
        s2 += __shfl_down(s2, o);
    }
    if ((threadIdx.x & 63) == 0) {
        atomicAdd(&scal[0], s1);
        atomicAdd(&scal[1], s2);
    }
}

__global__ __launch_bounds__(64) void k_bn_fin(const float* __restrict__ gamma,
                                               const float* __restrict__ beta,
                                               const float* __restrict__ lin_e,
                                               const float* __restrict__ att_e,
                                               float* __restrict__ scal) {
    int t = threadIdx.x;
    if (t == 0) {
        float mu = scal[0] / (float)NE;
        float var = scal[1] / (float)NE - mu * mu;
        float sc = gamma[0] * rsqrtf(var + EPSBN);
        scal[2] = sc;
        scal[3] = beta[0] - mu * sc;
    }
    if (t < 4) {
        float acc = 0.f;
        for (int c = 0; c < 64; ++c)
            acc += lin_e[t * 64 + c] * att_e[t * 64 + c];
        scal[4 + t] = acc;
    }
}

// ---------- normalize edges, degree, attr sum ----------
__global__ __launch_bounds__(256) void k_edge_norm(const float* __restrict__ ea,
                                                   const int* __restrict__ dst,
                                                   const float* __restrict__ scal,
                                                   float* __restrict__ enorm,
                                                   int* __restrict__ deg,
                                                   float* __restrict__ asum) {
    int e = blockIdx.x * blockDim.x + threadIdx.x;
    if (e >= NE) return;
    float v = log1pf(ea[e]) * scal[2] + scal[3];
    enorm[e] = v;
    int d = dst[e];
    atomicAdd(&deg[d], 1);
    atomicAdd(&asum[d], v);
}

__global__ __launch_bounds__(256) void k_loop_attr(const int* __restrict__ deg,
                                                   const float* __restrict__ asum,
                                                   float* __restrict__ lattr) {
    int n = blockIdx.x * blockDim.x + threadIdx.x;
    if (n >= NN) return;
    lattr[n] = asum[n] / fmaxf((float)deg[n], 1.f);
}

// ---------- GEMM: h = x @ W[m]  (50000x128 @ 128x256) ----------
__global__ __launch_bounds__(256) void k_gemm(const float* __restrict__ x,
                                              const float* __restrict__ Wm,
                                              float* __restrict__ h) {
    __shared__ float As[128 * 68];  // [k][row], pad 68
    __shared__ float Bs[128 * 68];  // [k][col], pad 68
    int t = threadIdx.x;
    int row0 = blockIdx.x * 64;
    int col0 = blockIdx.y * 64;
    #pragma unroll
    for (int i = 0; i < 32; ++i) {
        int e = i * 256 + t;
        int r = e >> 7, k = e & 127;
        float v = (row0 + r < NN) ? x[(size_t)(row0 + r) * IND + k] : 0.f;
        As[k * 68 + r] = v;
    }
    #pragma unroll
    for (int i = 0; i < 32; ++i) {
        int e = i * 256 + t;
        int k = e >> 6, c = e & 63;
        Bs[k * 68 + c] = Wm[k * HO + col0 + c];
    }
    __syncthreads();
    int tx = t & 15, ty = t >> 4;
    float acc[4][4];
    #pragma unroll
    for (int i = 0; i < 4; ++i)
        #pragma unroll
        for (int j = 0; j < 4; ++j) acc[i][j] = 0.f;
    #pragma unroll 8
    for (int k = 0; k < 128; ++k) {
        float4 a4 = *(const float4*)&As[k * 68 + 4 * ty];
        float4 b4 = *(const float4*)&Bs[k * 68 + 4 * tx];
        float av[4] = {a4.x, a4.y, a4.z, a4.w};
        float bv[4] = {b4.x, b4.y, b4.z, b4.w};
        #pragma unroll
        for (int i = 0; i < 4; ++i)
            #pragma unroll
            for (int j = 0; j < 4; ++j)
                acc[i][j] = fmaf(av[i], bv[j], acc[i][j]);
    }
    #pragma unroll
    for (int i = 0; i < 4; ++i) {
        int r = row0 + 4 * ty + i;
        if (r < NN) {
            float4 o = make_float4(acc[i][0], acc[i][1], acc[i][2], acc[i][3]);
            *(float4*)&h[(size_t)r * HO + col0 + 4 * tx] = o;
        }
    }
}

// ---------- per-node attention coefficients a_src_n, a_dst_n ----------
__global__ __launch_bounds__(256) void k_attn_node(const float* __restrict__ h,
                                                   const float* __restrict__ att_s,
                                                   const float* __restrict__ att_d,
                                                   float* __restrict__ asn,
                                                   float* __restrict__ adn) {
    int lane = threadIdx.x & 63;
    int n = (int)((blockIdx.x * (size_t)blockDim.x + threadIdx.x) >> 6);
    if (n >= NN) return;
    #pragma unroll
    for (int hh = 0; hh < NH; ++hh) {
        float v = h[(size_t)n * HO + hh * 64 + lane];
        float s = v * att_s[hh * 64 + lane];
        float d = v * att_d[hh * 64 + lane];
        #pragma unroll
        for (int o = 32; o > 0; o >>= 1) {
            s += __shfl_down(s, o);
            d += __shfl_down(d, o);
        }
        if (lane == 0) { asn[n * 4 + hh] = s; adn[n * 4 + hh] = d; }
    }
}

// ---------- pass A: alpha + segment max ----------
__global__ __launch_bounds__(256) void k_passA(const int* __restrict__ srcA,
                                               const int* __restrict__ dstA,
                                               const float* __restrict__ enorm,
                                               const float* __restrict__ lattr,
                                               const float* __restrict__ asn,
                                               const float* __restrict__ adn,
                                               const float* __restrict__ scal,
                                               float* __restrict__ alp,
                                               unsigned* __restrict__ mxu) {
    int e = blockIdx.x * blockDim.x + threadIdx.x;
    if (e >= NTOT) return;
    int s, d; float ev;
    if (e < NE) { s = srcA[e]; d = dstA[e]; ev = enorm[e]; }
    else { s = d = e - NE; ev = lattr[s]; }
    #pragma unroll
    for (int hh = 0; hh < NH; ++hh) {
        float a = asn[s * 4 + hh] + adn[d * 4 + hh] + ev * scal[4 + hh];
        a = (a >= 0.f) ? a : SLOPE * a;
        alp[(size_t)e * 4 + hh] = a;
        atomicMax(&mxu[d * 4 + hh], fkey(a));
    }
}

// ---------- pass B: exp + segment denom ----------
__global__ __launch_bounds__(256) void k_passB(const int* __restrict__ dstA,
                                               const unsigned* __restrict__ mxu,
                                               float* __restrict__ alp,
                                               float* __restrict__ denom) {
    int e = blockIdx.x * blockDim.x + threadIdx.x;
    if (e >= NTOT) return;
    int d = (e < NE) ? dstA[e] : (e - NE);
    #pragma unroll
    for (int hh = 0; hh < NH; ++hh) {
        float m = fkey_inv(mxu[d * 4 + hh]);
        float ex = expf(alp[(size_t)e * 4 + hh] - m);
        alp[(size_t)e * 4 + hh] = ex;
        atomicAdd(&denom[d * 4 + hh], ex);
    }
}

// ---------- pass C: weighted gather-scatter (wave per edge) ----------
__global__ __launch_bounds__(256) void k_passC(const int* __restrict__ srcA,
                                               const int* __restrict__ dstA,
                                               const float* __restrict__ alp,
                                               const float* __restrict__ denom,
                                               const float* __restrict__ h,
                                               float* __restrict__ zall,
                                               int mslice) {
    int lane = threadIdx.x & 63;
    int wid = (int)((blockIdx.x * (size_t)blockDim.x + threadIdx.x) >> 6);
    int nw = (gridDim.x * blockDim.x) >> 6;
    for (int e = wid; e < NTOT; e += nw) {
        int s, d;
        if (e < NE) { s = srcA[e]; d = dstA[e]; }
        else { s = d = e - NE; }
        float w[NH];
        #pragma unroll
        for (int hh = 0; hh < NH; ++hh)
            w[hh] = alp[(size_t)e * 4 + hh] / denom[d * 4 + hh];
        const float* hr = &h[(size_t)s * HO];
        float val = 0.f;
        #pragma unroll
        for (int hh = 0; hh < NH; ++hh)
            val += w[hh] * hr[hh * 64 + lane];
        atomicAdd(&zall[(size_t)d * 192 + mslice * 64 + lane], 0.25f * val);
    }
}

// ---------- bias + elu ----------
__global__ __launch_bounds__(256) void k_bias_elu(float* __restrict__ zall,
                                                  const float* __restrict__ bias,
                                                  int mslice) {
    int i = blockIdx.x * blockDim.x + threadIdx.x;
    if (i >= NN * 64) return;
    int n = i >> 6, c = i & 63;
    float z = zall[(size_t)n * 192 + mslice * 64 + c] + bias[c];
    zall[(size_t)n * 192 + mslice * 64 + c] = (z > 0.f) ? z : expm1f(z);
}

// ---------- semantic attention (wave per node) ----------
__global__ __launch_bounds__(256) void k_semantic(const float* __restrict__ zall,
                                                  const float* __restrict__ semW,
                                                  const float* __restrict__ semb,
                                                  const float* __restrict__ avec,
                                                  float* __restrict__ out) {
    __shared__ float Ws[64 * 64];
    int t = threadIdx.x;
    #pragma unroll
    for (int i = 0; i < 16; ++i) Ws[i * 256 + t] = semW[i * 256 + t];
    __syncthreads();
    int lane = t & 63;
    int n = blockIdx.x * 4 + (t >> 6);
    if (n >= NN) return;
    float zv[NM];
    #pragma unroll
    for (int m = 0; m < NM; ++m) zv[m] = zall[(size_t)n * 192 + m * 64 + lane];
    float score[NM];
    #pragma unroll
    for (int m = 0; m < NM; ++m) {
        float wg = semb[lane];
        #pragma unroll 8
        for (int k = 0; k < 64; ++k)
            wg = fmaf(__shfl(zv[m], k), Ws[k * 64 + lane], wg);
        wg = tanhf(wg);
        float p = wg * avec[lane];
        #pragma unroll
        for (int o = 32; o > 0; o >>= 1) p += __shfl_xor(p, o);
        score[m] = p;
    }
    float mx = fmaxf(fmaxf(score[0], score[1]), score[2]);
    float e0 = expf(score[0] - mx), e1 = expf(score[1] - mx), e2 = expf(score[2] - mx);
    float inv = 1.f / (e0 + e1 + e2);
    float b0 = e0 * inv, b1 = e1 * inv, b2 = e2 * inv;
    out[(size_t)n * 64 + lane] = b0 * zv[0] + b1 * zv[1] + b2 * zv[2];
    if (lane < 3) {
        float b = (lane == 0) ? b0 : (lane == 1) ? b1 : b2;
        out[(size_t)NN * 64 + (size_t)n * 3 + lane] = b;
    }
}

// ---------- host ----------
extern "C" void kernel_launch(void* const* d_in, const int* in_sizes, int n_in,
                              void* d_out, int out_size, void* d_ws, size_t ws_size,
                              hipStream_t stream) {
    (void)in_sizes; (void)n_in; (void)out_size; (void)ws_size;
    const float* x        = (const float*)d_in[0];
    const int*   ei       = (const int*)d_in[1];
    const float* eattr    = (const float*)d_in[2];
    const float* W        = (const float*)d_in[3];
    const float* att_src  = (const float*)d_in[4];
    const float* att_dst  = (const float*)d_in[5];
    const float* lin_edge = (const float*)d_in[6];
    const float* att_edge = (const float*)d_in[7];
    const float* bias     = (const float*)d_in[8];
    const float* bn_gamma = (const float*)d_in[9];
    const float* bn_beta  = (const float*)d_in[10];
    const float* sem_W    = (const float*)d_in[11];
    const float* sem_b    = (const float*)d_in[12];
    const float* attn_vec = (const float*)d_in[13];
    float* out = (float*)d_out;

    float* ws = (float*)d_ws;
    size_t o = 0;
    float* h     = ws + o; o += (size_t)NN * 256;
    float* zall  = ws + o; o += (size_t)NN * 192;
    float* asn   = ws + o; o += (size_t)NN * 4;
    float* adn   = ws + o; o += (size_t)NN * 4;
    unsigned* mxu = (unsigned*)(ws + o); o += (size_t)NN * 4;
    float* denom = ws + o; o += (size_t)NN * 4;
    float* alp   = ws + o; o += (size_t)NTOT * 4;
    float* enorm = ws + o; o += (size_t)NE;
    int*   deg   = (int*)(ws + o); o += (size_t)NN;
    float* asum  = ws + o; o += (size_t)NN;
    float* lattr = ws + o; o += (size_t)NN;
    float* scal  = ws + o; o += 16;
    // total ~25.6M floats = ~102 MB

    k_init_zall<<<(NN * 192 + 255) / 256, 256, 0, stream>>>(zall);

    for (int m = 0; m < NM; ++m) {
        const int* srcA = ei + (size_t)m * 2 * NE;
        const int* dstA = srcA + NE;
        const float* eam = eattr + (size_t)m * NE;

        k_init_m<<<(NN * 4 + 255) / 256, 256, 0, stream>>>(mxu, denom, deg, asum, scal);
        k_bn_reduce<<<1024, 256, 0, stream>>>(eam, scal);
        k_bn_fin<<<1, 64, 0, stream>>>(bn_gamma + m, bn_beta + m,
                                       lin_edge + (size_t)m * HO,
                                       att_edge + (size_t)m * HO, scal);
        k_edge_norm<<<(NE + 255) / 256, 256, 0, stream>>>(eam, dstA, scal, enorm, deg, asum);
        k_loop_attr<<<(NN + 255) / 256, 256, 0, stream>>>(deg, asum, lattr);
        {
            dim3 g((NN + 63) / 64, HO / 64);
            k_gemm<<<g, 256, 0, stream>>>(x, W + (size_t)m * IND * HO, h);
        }
        k_attn_node<<<(NN * 64 + 255) / 256, 256, 0, stream>>>(
            h, att_src + (size_t)m * HO, att_dst + (size_t)m * HO, asn, adn);
        k_passA<<<(NTOT + 255) / 256, 256, 0, stream>>>(srcA, dstA, enorm, lattr,
                                                        asn, adn, scal, alp, mxu);
        k_passB<<<(NTOT + 255) / 256, 256, 0, stream>>>(dstA, mxu, alp, denom);
        k_passC<<<4096, 256, 0, stream>>>(srcA, dstA, alp, denom, h, zall, m);
        k_bias_elu<<<(NN * 64 + 255) / 256, 256, 0, stream>>>(zall, bias + (size_t)m * 64, m);
    }

    k_semantic<<<(NN + 3) / 4, 256, 0, stream>>>(zall, sem_W, sem_b, attn_vec, out);
}

// Round 2
// 1259.612 us; speedup vs baseline: 1.5404x; 1.5404x over previous
//
#include <hip/hip_runtime.h>
#include <hip/hip_bf16.h>
#include <math.h>

#define NN 50000
#define NE 400000
#define NM 3
#define IND 128
#define OUTD 64
#define NH 4
#define HO 256          // NH*OUTD
#define EPSBN 1e-5f
#define SLOPE 0.2f
#define NTOT (NE + NN)  // edges + self loops

// ---------- init: zero all accumulated ws buffers ----------
__global__ __launch_bounds__(256) void k_init(float* __restrict__ zall,
                                              float* __restrict__ denom3,
                                              float* __restrict__ asum3,
                                              int* __restrict__ deg3,
                                              float* __restrict__ scal3) {
    size_t i = (size_t)blockIdx.x * blockDim.x + threadIdx.x;
    if (i < (size_t)NN * 192) zall[i] = 0.f;
    if (i < (size_t)NM * NN * 4) denom3[i] = 0.f;
    if (i < (size_t)NM * NN) { asum3[i] = 0.f; deg3[i] = 0; }
    if (i < NM * 16) scal3[i] = 0.f;
}

// ---------- BatchNorm stats over log1p(edge_attr), all m ----------
__global__ __launch_bounds__(256) void k_bn_reduce(const float* __restrict__ eattr,
                                                   float* __restrict__ scal3) {
    int m = blockIdx.y;
    const float* ea = eattr + (size_t)m * NE;
    int i = blockIdx.x * blockDim.x + threadIdx.x;
    int stride = gridDim.x * blockDim.x;
    float s1 = 0.f, s2 = 0.f;
    for (int e = i; e < NE; e += stride) {
        float v = log1pf(ea[e]);
        s1 += v; s2 += v * v;
    }
    #pragma unroll
    for (int o = 32; o > 0; o >>= 1) {
        s1 += __shfl_down(s1, o);
        s2 += __shfl_down(s2, o);
    }
    if ((threadIdx.x & 63) == 0) {
        atomicAdd(&scal3[m * 16 + 0], s1);
        atomicAdd(&scal3[m * 16 + 1], s2);
    }
}

__global__ __launch_bounds__(64) void k_bn_fin(const float* __restrict__ gamma,
                                               const float* __restrict__ beta,
                                               const float* __restrict__ lin_edge,
                                               const float* __restrict__ att_edge,
                                               float* __restrict__ scal3) {
    int m = blockIdx.x;
    int t = threadIdx.x;
    float* scal = scal3 + m * 16;
    if (t == 0) {
        float mu = scal[0] / (float)NE;
        float var = scal[1] / (float)NE - mu * mu;
        float sc = gamma[m] * rsqrtf(var + EPSBN);
        scal[2] = sc;
        scal[3] = beta[m] - mu * sc;
    }
    if (t < 4) {
        const float* le = lin_edge + (size_t)m * HO;
        const float* ae = att_edge + (size_t)m * HO;
        float acc = 0.f;
        for (int c = 0; c < 64; ++c)
            acc += le[t * 64 + c] * ae[t * 64 + c];
        scal[4 + t] = acc;
    }
}

// ---------- degree + normalized-attr sum per destination, all m ----------
__global__ __launch_bounds__(256) void k_edge_deg(const float* __restrict__ eattr,
                                                  const int* __restrict__ ei,
                                                  const float* __restrict__ scal3,
                                                  int* __restrict__ deg3,
                                                  float* __restrict__ asum3) {
    int m = blockIdx.y;
    int e = blockIdx.x * blockDim.x + threadIdx.x;
    if (e >= NE) return;
    const float* ea = eattr + (size_t)m * NE;
    const int* dst = ei + (size_t)m * 2 * NE + NE;
    float v = log1pf(ea[e]) * scal3[m * 16 + 2] + scal3[m * 16 + 3];
    int d = dst[e];
    atomicAdd(&deg3[(size_t)m * NN + d], 1);
    atomicAdd(&asum3[(size_t)m * NN + d], v);
}

// ---------- GEMM: h = x @ W[m]  + fused a_src/a_dst epilogue ----------
__global__ __launch_bounds__(256) void k_gemm(const float* __restrict__ x,
                                              const float* __restrict__ Wm,
                                              const float* __restrict__ att_s,
                                              const float* __restrict__ att_d,
                                              float* __restrict__ h,
                                              float* __restrict__ asn,
                                              float* __restrict__ adn) {
    __shared__ float As[128 * 68];  // [k][row], pad 68
    __shared__ float Bs[128 * 68];  // [k][col], pad 68
    int t = threadIdx.x;
    int row0 = blockIdx.x * 64;
    int col0 = blockIdx.y * 64;   // = head * 64
    #pragma unroll
    for (int i = 0; i < 32; ++i) {
        int e = i * 256 + t;
        int r = e >> 7, k = e & 127;
        float v = (row0 + r < NN) ? x[(size_t)(row0 + r) * IND + k] : 0.f;
        As[k * 68 + r] = v;
    }
    #pragma unroll
    for (int i = 0; i < 32; ++i) {
        int e = i * 256 + t;
        int k = e >> 6, c = e & 63;
        Bs[k * 68 + c] = Wm[k * HO + col0 + c];
    }
    __syncthreads();
    int tx = t & 15, ty = t >> 4;
    float acc[4][4];
    #pragma unroll
    for (int i = 0; i < 4; ++i)
        #pragma unroll
        for (int j = 0; j < 4; ++j) acc[i][j] = 0.f;
    #pragma unroll 8
    for (int k = 0; k < 128; ++k) {
        float4 a4 = *(const float4*)&As[k * 68 + 4 * ty];
        float4 b4 = *(const float4*)&Bs[k * 68 + 4 * tx];
        float av[4] = {a4.x, a4.y, a4.z, a4.w};
        float bv[4] = {b4.x, b4.y, b4.z, b4.w};
        #pragma unroll
        for (int i = 0; i < 4; ++i)
            #pragma unroll
            for (int j = 0; j < 4; ++j)
                acc[i][j] = fmaf(av[i], bv[j], acc[i][j]);
    }
    // store h tile
    #pragma unroll
    for (int i = 0; i < 4; ++i) {
        int r = row0 + 4 * ty + i;
        if (r < NN) {
            float4 o = make_float4(acc[i][0], acc[i][1], acc[i][2], acc[i][3]);
            *(float4*)&h[(size_t)r * HO + col0 + 4 * tx] = o;
        }
    }
    // fused per-node attention coefficients: this block covers one full head
    int hh = blockIdx.y;
    float as4[4], ad4[4];
    #pragma unroll
    for (int j = 0; j < 4; ++j) {
        as4[j] = att_s[col0 + 4 * tx + j];
        ad4[j] = att_d[col0 + 4 * tx + j];
    }
    #pragma unroll
    for (int i = 0; i < 4; ++i) {
        float s = 0.f, d = 0.f;
        #pragma unroll
        for (int j = 0; j < 4; ++j) {
            s = fmaf(acc[i][j], as4[j], s);
            d = fmaf(acc[i][j], ad4[j], d);
        }
        #pragma unroll
        for (int o = 8; o > 0; o >>= 1) {
            s += __shfl_xor(s, o, 16);
            d += __shfl_xor(d, o, 16);
        }
        int r = row0 + 4 * ty + i;
        if (tx == 0 && r < NN) {
            asn[r * 4 + hh] = s;
            adn[r * 4 + hh] = d;
        }
    }
}

// ---------- pass AB: alpha -> exp(alpha), denom accumulate (no segment max) ----------
__global__ __launch_bounds__(256) void k_passAB(const int* __restrict__ srcA,
                                                const int* __restrict__ dstA,
                                                const float* __restrict__ ea,
                                                const int* __restrict__ deg,
                                                const float* __restrict__ asum,
                                                const float* __restrict__ scal,
                                                const float* __restrict__ asn,
                                                const float* __restrict__ adn,
                                                float* __restrict__ denom,
                                                float* __restrict__ alp) {
    int e = blockIdx.x * blockDim.x + threadIdx.x;
    if (e >= NTOT) return;
    int s, d; float ev;
    if (e < NE) {
        s = srcA[e]; d = dstA[e];
        ev = log1pf(ea[e]) * scal[2] + scal[3];
    } else {
        s = d = e - NE;
        ev = asum[s] / fmaxf((float)deg[s], 1.f);
    }
    float4 as4 = *(const float4*)&asn[s * 4];
    float4 ad4 = *(const float4*)&adn[d * 4];
    float av[4] = {as4.x + ad4.x, as4.y + ad4.y, as4.z + ad4.z, as4.w + ad4.w};
    float ex[4];
    #pragma unroll
    for (int hh = 0; hh < NH; ++hh) {
        float a = av[hh] + ev * scal[4 + hh];
        a = (a >= 0.f) ? a : SLOPE * a;
        ex[hh] = expf(a);
        atomicAdd(&denom[d * 4 + hh], ex[hh]);
    }
    *(float4*)&alp[(size_t)e * 4] = make_float4(ex[0], ex[1], ex[2], ex[3]);
}

// ---------- pass C: weighted gather-scatter (wave per edge) ----------
__global__ __launch_bounds__(256) void k_passC(const int* __restrict__ srcA,
                                               const int* __restrict__ dstA,
                                               const float* __restrict__ alp,
                                               const float* __restrict__ denom,
                                               const float* __restrict__ h,
                                               float* __restrict__ zall,
                                               int mslice) {
    int lane = threadIdx.x & 63;
    int wid = (int)((blockIdx.x * (size_t)blockDim.x + threadIdx.x) >> 6);
    int nw = (gridDim.x * blockDim.x) >> 6;
    for (int e = wid; e < NTOT; e += nw) {
        int s, d;
        if (e < NE) { s = srcA[e]; d = dstA[e]; }
        else { s = d = e - NE; }
        float4 ex4 = *(const float4*)&alp[(size_t)e * 4];
        float4 dn4 = *(const float4*)&denom[d * 4];
        float w0 = ex4.x * __builtin_amdgcn_rcpf(dn4.x);
        float w1 = ex4.y * __builtin_amdgcn_rcpf(dn4.y);
        float w2 = ex4.z * __builtin_amdgcn_rcpf(dn4.z);
        float w3 = ex4.w * __builtin_amdgcn_rcpf(dn4.w);
        const float* hr = &h[(size_t)s * HO];
        float val = w0 * hr[lane] + w1 * hr[64 + lane]
                  + w2 * hr[128 + lane] + w3 * hr[192 + lane];
        atomicAdd(&zall[(size_t)d * 192 + mslice * 64 + lane], 0.25f * val);
    }
}

// ---------- bias + elu, all m at once ----------
__global__ __launch_bounds__(256) void k_bias_elu(float* __restrict__ zall,
                                                  const float* __restrict__ bias) {
    int i = blockIdx.x * blockDim.x + threadIdx.x;
    if (i >= NN * 192) return;
    int r = i % 192;           // m*64 + c
    float z = zall[i] + bias[r];
    zall[i] = (z > 0.f) ? z : expm1f(z);
}

// ---------- semantic attention: sem_W column in VGPRs, z via LDS broadcast ----------
__global__ __launch_bounds__(256) void k_semantic(const float* __restrict__ zall,
                                                  const float* __restrict__ semW,
                                                  const float* __restrict__ semb,
                                                  const float* __restrict__ avec,
                                                  float* __restrict__ out) {
    __shared__ float zbuf[4][192];
    int t = threadIdx.x;
    int lane = t & 63;
    int wid = t >> 6;
    // each lane holds column `lane` of sem_W in registers (static indices only)
    float wsc[64];
    #pragma unroll
    for (int k = 0; k < 64; ++k) wsc[k] = semW[k * 64 + lane];
    float sb = semb[lane];
    float av = avec[lane];
    int gw = blockIdx.x * 4 + wid;
    int nwv = gridDim.x * 4;
    for (int n = gw; n < NN; n += nwv) {
        float zm0 = zall[(size_t)n * 192 + lane];
        float zm1 = zall[(size_t)n * 192 + 64 + lane];
        float zm2 = zall[(size_t)n * 192 + 128 + lane];
        zbuf[wid][lane] = zm0;
        zbuf[wid][64 + lane] = zm1;
        zbuf[wid][128 + lane] = zm2;
        float sc3[3];
        #pragma unroll
        for (int m = 0; m < 3; ++m) {
            float a0 = sb, a1 = 0.f, a2 = 0.f, a3 = 0.f;
            #pragma unroll
            for (int k4 = 0; k4 < 16; ++k4) {
                float4 z4 = *(const float4*)&zbuf[wid][m * 64 + k4 * 4];
                a0 = fmaf(z4.x, wsc[k4 * 4 + 0], a0);
                a1 = fmaf(z4.y, wsc[k4 * 4 + 1], a1);
                a2 = fmaf(z4.z, wsc[k4 * 4 + 2], a2);
                a3 = fmaf(z4.w, wsc[k4 * 4 + 3], a3);
            }
            float wg = tanhf((a0 + a1) + (a2 + a3));
            float p = wg * av;
            #pragma unroll
            for (int o = 32; o > 0; o >>= 1) p += __shfl_xor(p, o);
            sc3[m] = p;
        }
        float mx = fmaxf(sc3[0], fmaxf(sc3[1], sc3[2]));
        float e0 = expf(sc3[0] - mx), e1 = expf(sc3[1] - mx), e2 = expf(sc3[2] - mx);
        float inv = 1.f / (e0 + e1 + e2);
        float b0 = e0 * inv, b1 = e1 * inv, b2 = e2 * inv;
        out[(size_t)n * 64 + lane] = b0 * zm0 + b1 * zm1 + b2 * zm2;
        if (lane < 3) {
            float b = (lane == 0) ? b0 : (lane == 1) ? b1 : b2;
            out[(size_t)NN * 64 + (size_t)n * 3 + lane] = b;
        }
    }
}

// ---------- host ----------
extern "C" void kernel_launch(void* const* d_in, const int* in_sizes, int n_in,
                              void* d_out, int out_size, void* d_ws, size_t ws_size,
                              hipStream_t stream) {
    (void)in_sizes; (void)n_in; (void)out_size; (void)ws_size;
    const float* x        = (const float*)d_in[0];
    const int*   ei       = (const int*)d_in[1];
    const float* eattr    = (const float*)d_in[2];
    const float* W        = (const float*)d_in[3];
    const float* att_src  = (const float*)d_in[4];
    const float* att_dst  = (const float*)d_in[5];
    const float* lin_edge = (const float*)d_in[6];
    const float* att_edge = (const float*)d_in[7];
    const float* bias     = (const float*)d_in[8];
    const float* bn_gamma = (const float*)d_in[9];
    const float* bn_beta  = (const float*)d_in[10];
    const float* sem_W    = (const float*)d_in[11];
    const float* sem_b    = (const float*)d_in[12];
    const float* attn_vec = (const float*)d_in[13];
    float* out = (float*)d_out;

    float* ws = (float*)d_ws;
    size_t o = 0;
    float* h      = ws + o; o += (size_t)NN * 256;   // 12.8M
    float* zall   = ws + o; o += (size_t)NN * 192;   //  9.6M
    float* alp    = ws + o; o += (size_t)NTOT * 4;   //  1.8M
    float* asn    = ws + o; o += (size_t)NN * 4;
    float* adn    = ws + o; o += (size_t)NN * 4;
    float* denom3 = ws + o; o += (size_t)NM * NN * 4;
    float* asum3  = ws + o; o += (size_t)NM * NN;
    int*   deg3   = (int*)(ws + o); o += (size_t)NM * NN;
    float* scal3  = ws + o; o += NM * 16;
    // total ~25.5M floats = 102.0 MB

    k_init<<<(NN * 192 + 255) / 256, 256, 0, stream>>>(zall, denom3, asum3, deg3, scal3);
    k_bn_reduce<<<dim3(256, NM), 256, 0, stream>>>(eattr, scal3);
    k_bn_fin<<<NM, 64, 0, stream>>>(bn_gamma, bn_beta, lin_edge, att_edge, scal3);
    k_edge_deg<<<dim3((NE + 255) / 256, NM), 256, 0, stream>>>(eattr, ei, scal3, deg3, asum3);

    for (int m = 0; m < NM; ++m) {
        const int* srcA = ei + (size_t)m * 2 * NE;
        const int* dstA = srcA + NE;
        const float* eam = eattr + (size_t)m * NE;
        float* denom = denom3 + (size_t)m * NN * 4;

        k_gemm<<<dim3((NN + 63) / 64, NH), 256, 0, stream>>>(
            x, W + (size_t)m * IND * HO,
            att_src + (size_t)m * HO, att_dst + (size_t)m * HO,
            h, asn, adn);
        k_passAB<<<(NTOT + 255) / 256, 256, 0, stream>>>(
            srcA, dstA, eam, deg3 + (size_t)m * NN, asum3 + (size_t)m * NN,
            scal3 + m * 16, asn, adn, denom, alp);
        k_passC<<<4096, 256, 0, stream>>>(srcA, dstA, alp, denom, h, zall, m);
    }

    k_bias_elu<<<(NN * 192 + 255) / 256, 256, 0, stream>>>(zall, bias);
    k_semantic<<<2048, 256, 0, stream>>>(zall, sem_W, sem_b, attn_vec, out);
}

// Round 3
// 976.521 us; speedup vs baseline: 1.9870x; 1.2899x over previous
//
#include <hip/hip_runtime.h>
#include <hip/hip_bf16.h>
#include <math.h>

#define NN 50000
#define NE 400000
#define NM 3
#define IND 128
#define OUTD 64
#define NH 4
#define HO 256          // NH*OUTD
#define EPSBN 1e-5f
#define SLOPE 0.2f

// ---------- bf16 helpers (RNE) ----------
__device__ __forceinline__ unsigned short f2bf(float f) {
    unsigned u = __float_as_uint(f);
    unsigned r = (u + 0x7FFFu + ((u >> 16) & 1u)) >> 16;
    return (unsigned short)r;
}
__device__ __forceinline__ float bf2f(unsigned short b) {
    return __uint_as_float(((unsigned)b) << 16);
}

// ---------- init: zero accumulated buffers ----------
__global__ __launch_bounds__(256) void k_init(int* __restrict__ deg3,
                                              float* __restrict__ asum3,
                                              float* __restrict__ scal3) {
    size_t i = (size_t)blockIdx.x * blockDim.x + threadIdx.x;
    if (i < (size_t)NM * NN) { deg3[i] = 0; asum3[i] = 0.f; }
    if (i < NM * 16) scal3[i] = 0.f;
}

// ---------- BatchNorm stats over log1p(edge_attr), all m ----------
__global__ __launch_bounds__(256) void k_bn_reduce(const float* __restrict__ eattr,
                                                   float* __restrict__ scal3) {
    int m = blockIdx.y;
    const float* ea = eattr + (size_t)m * NE;
    int i = blockIdx.x * blockDim.x + threadIdx.x;
    int stride = gridDim.x * blockDim.x;
    float s1 = 0.f, s2 = 0.f;
    for (int e = i; e < NE; e += stride) {
        float v = log1pf(ea[e]);
        s1 += v; s2 += v * v;
    }
    #pragma unroll
    for (int o = 32; o > 0; o >>= 1) {
        s1 += __shfl_down(s1, o);
        s2 += __shfl_down(s2, o);
    }
    if ((threadIdx.x & 63) == 0) {
        atomicAdd(&scal3[m * 16 + 0], s1);
        atomicAdd(&scal3[m * 16 + 1], s2);
    }
}

__global__ __launch_bounds__(64) void k_bn_fin(const float* __restrict__ gamma,
                                               const float* __restrict__ beta,
                                               const float* __restrict__ lin_edge,
                                               const float* __restrict__ att_edge,
                                               float* __restrict__ scal3) {
    int m = blockIdx.x;
    int t = threadIdx.x;
    float* scal = scal3 + m * 16;
    if (t == 0) {
        float mu = scal[0] / (float)NE;
        float var = scal[1] / (float)NE - mu * mu;
        float sc = gamma[m] * rsqrtf(var + EPSBN);
        scal[2] = sc;
        scal[3] = beta[m] - mu * sc;
    }
    if (t < 4) {
        const float* le = lin_edge + (size_t)m * HO;
        const float* ae = att_edge + (size_t)m * HO;
        float acc = 0.f;
        for (int c = 0; c < 64; ++c)
            acc += le[t * 64 + c] * ae[t * 64 + c];
        scal[4 + t] = acc;
    }
}

// ---------- degree + normalized-attr sum per destination, all m ----------
__global__ __launch_bounds__(256) void k_edge_deg(const float* __restrict__ eattr,
                                                  const int* __restrict__ ei,
                                                  const float* __restrict__ scal3,
                                                  int* __restrict__ deg3,
                                                  float* __restrict__ asum3) {
    int m = blockIdx.y;
    int e = blockIdx.x * blockDim.x + threadIdx.x;
    if (e >= NE) return;
    const float* ea = eattr + (size_t)m * NE;
    const int* dst = ei + (size_t)m * 2 * NE + NE;
    float v = log1pf(ea[e]) * scal3[m * 16 + 2] + scal3[m * 16 + 3];
    int d = dst[e];
    atomicAdd(&deg3[(size_t)m * NN + d], 1);
    atomicAdd(&asum3[(size_t)m * NN + d], v);
}

// ---------- exclusive scan of degrees -> CSR ptr + scatter cursor ----------
__global__ __launch_bounds__(1024) void k_scan(const int* __restrict__ deg3,
                                               int* __restrict__ ptr3,
                                               int* __restrict__ cur3) {
    int m = blockIdx.x;
    const int* deg = deg3 + (size_t)m * NN;
    int* ptr = ptr3 + (size_t)m * (NN + 1);
    int* cur = cur3 + (size_t)m * NN;
    __shared__ int part[1024];
    int t = threadIdx.x;
    const int CH = (NN + 1023) / 1024;   // 49
    int base = t * CH;
    int s = 0;
    for (int i = 0; i < CH; ++i) {
        int idx = base + i;
        if (idx < NN) s += deg[idx];
    }
    part[t] = s;
    __syncthreads();
    for (int o = 1; o < 1024; o <<= 1) {
        int v = (t >= o) ? part[t - o] : 0;
        __syncthreads();
        part[t] += v;
        __syncthreads();
    }
    int run = (t == 0) ? 0 : part[t - 1];
    for (int i = 0; i < CH; ++i) {
        int idx = base + i;
        if (idx < NN) {
            ptr[idx] = run;
            cur[idx] = run;
            run += deg[idx];
        }
    }
    if (t == 1023) ptr[NN] = run;
}

// ---------- GEMM: h(bf16) = x @ W[m], fused a_src/a_dst epilogue ----------
__global__ __launch_bounds__(256) void k_gemm(const float* __restrict__ x,
                                              const float* __restrict__ Wm,
                                              const float* __restrict__ att_s,
                                              const float* __restrict__ att_d,
                                              unsigned short* __restrict__ hbf,
                                              float* __restrict__ asn,
                                              float* __restrict__ adn) {
    __shared__ float As[128 * 68];  // [k][row], pad 68
    __shared__ float Bs[128 * 68];  // [k][col], pad 68
    int t = threadIdx.x;
    int row0 = blockIdx.x * 64;
    int col0 = blockIdx.y * 64;   // = head * 64
    #pragma unroll
    for (int i = 0; i < 32; ++i) {
        int e = i * 256 + t;
        int r = e >> 7, k = e & 127;
        float v = (row0 + r < NN) ? x[(size_t)(row0 + r) * IND + k] : 0.f;
        As[k * 68 + r] = v;
    }
    #pragma unroll
    for (int i = 0; i < 32; ++i) {
        int e = i * 256 + t;
        int k = e >> 6, c = e & 63;
        Bs[k * 68 + c] = Wm[k * HO + col0 + c];
    }
    __syncthreads();
    int tx = t & 15, ty = t >> 4;
    float acc[4][4];
    #pragma unroll
    for (int i = 0; i < 4; ++i)
        #pragma unroll
        for (int j = 0; j < 4; ++j) acc[i][j] = 0.f;
    #pragma unroll 8
    for (int k = 0; k < 128; ++k) {
        float4 a4 = *(const float4*)&As[k * 68 + 4 * ty];
        float4 b4 = *(const float4*)&Bs[k * 68 + 4 * tx];
        float av[4] = {a4.x, a4.y, a4.z, a4.w};
        float bv[4] = {b4.x, b4.y, b4.z, b4.w};
        #pragma unroll
        for (int i = 0; i < 4; ++i)
            #pragma unroll
            for (int j = 0; j < 4; ++j)
                acc[i][j] = fmaf(av[i], bv[j], acc[i][j]);
    }
    // store h tile (bf16)
    #pragma unroll
    for (int i = 0; i < 4; ++i) {
        int r = row0 + 4 * ty + i;
        if (r < NN) {
            ushort4 o;
            o.x = f2bf(acc[i][0]); o.y = f2bf(acc[i][1]);
            o.z = f2bf(acc[i][2]); o.w = f2bf(acc[i][3]);
            *(ushort4*)&hbf[(size_t)r * HO + col0 + 4 * tx] = o;
        }
    }
    // fused per-node attention coefficients (fp32 acc)
    int hh = blockIdx.y;
    float as4[4], ad4[4];
    #pragma unroll
    for (int j = 0; j < 4; ++j) {
        as4[j] = att_s[col0 + 4 * tx + j];
        ad4[j] = att_d[col0 + 4 * tx + j];
    }
    #pragma unroll
    for (int i = 0; i < 4; ++i) {
        float s = 0.f, d = 0.f;
        #pragma unroll
        for (int j = 0; j < 4; ++j) {
            s = fmaf(acc[i][j], as4[j], s);
            d = fmaf(acc[i][j], ad4[j], d);
        }
        #pragma unroll
        for (int o = 8; o > 0; o >>= 1) {
            s += __shfl_xor(s, o, 16);
            d += __shfl_xor(d, o, 16);
        }
        int r = row0 + 4 * ty + i;
        if (tx == 0 && r < NN) {
            asn[r * 4 + hh] = s;
            adn[r * 4 + hh] = d;
        }
    }
}

// ---------- scatter: alpha -> exp(alpha), write CSR (src, ex4) ----------
__global__ __launch_bounds__(256) void k_scatter(const int* __restrict__ srcA,
                                                 const int* __restrict__ dstA,
                                                 const float* __restrict__ ea,
                                                 const float* __restrict__ scal,
                                                 const float* __restrict__ asn,
                                                 const float* __restrict__ adn,
                                                 int* __restrict__ cur,
                                                 int* __restrict__ csrc,
                                                 float* __restrict__ cex) {
    int e = blockIdx.x * blockDim.x + threadIdx.x;
    if (e >= NE) return;
    int s = srcA[e], d = dstA[e];
    float ev = log1pf(ea[e]) * scal[2] + scal[3];
    float4 as4 = *(const float4*)&asn[s * 4];
    float4 ad4 = *(const float4*)&adn[d * 4];
    float av[4] = {as4.x + ad4.x, as4.y + ad4.y, as4.z + ad4.z, as4.w + ad4.w};
    float ex[4];
    #pragma unroll
    for (int hh = 0; hh < NH; ++hh) {
        float a = av[hh] + ev * scal[4 + hh];
        a = (a >= 0.f) ? a : SLOPE * a;
        ex[hh] = expf(a);
    }
    int pos = atomicAdd(&cur[d], 1);
    csrc[pos] = s;
    *(float4*)&cex[(size_t)pos * 4] = make_float4(ex[0], ex[1], ex[2], ex[3]);
}

// ---------- pass C: wave per destination, register accumulate, no atomics ----------
__global__ __launch_bounds__(256) void k_passC(const int* __restrict__ ptr,
                                               const int* __restrict__ csrc,
                                               const float* __restrict__ cex,
                                               const unsigned short* __restrict__ hbf,
                                               const float* __restrict__ asn,
                                               const float* __restrict__ adn,
                                               const int* __restrict__ deg,
                                               const float* __restrict__ asum,
                                               const float* __restrict__ scal,
                                               const float* __restrict__ bias,
                                               float* __restrict__ zall,
                                               int mslice) {
    int lane = threadIdx.x & 63;
    int d = (int)((blockIdx.x * (size_t)blockDim.x + threadIdx.x) >> 6);
    if (d >= NN) return;
    // self-loop term
    float4 as4 = *(const float4*)&asn[d * 4];
    float4 ad4 = *(const float4*)&adn[d * 4];
    float ev = asum[d] / fmaxf((float)deg[d], 1.f);
    float av[4] = {as4.x + ad4.x, as4.y + ad4.y, as4.z + ad4.z, as4.w + ad4.w};
    float den[4], acc[4];
    const unsigned short* hd = &hbf[(size_t)d * HO];
    #pragma unroll
    for (int hh = 0; hh < NH; ++hh) {
        float a = av[hh] + ev * scal[4 + hh];
        a = (a >= 0.f) ? a : SLOPE * a;
        float exs = expf(a);
        den[hh] = exs;
        acc[hh] = exs * bf2f(hd[hh * 64 + lane]);
    }
    int p0 = ptr[d], p1 = ptr[d + 1];
    for (int p = p0; p < p1; ++p) {
        int s = csrc[p];                                  // wave-uniform broadcast
        float4 e4 = *(const float4*)&cex[(size_t)p * 4];  // broadcast
        const unsigned short* hs = &hbf[(size_t)s * HO];
        den[0] += e4.x; den[1] += e4.y; den[2] += e4.z; den[3] += e4.w;
        acc[0] = fmaf(e4.x, bf2f(hs[lane]), acc[0]);
        acc[1] = fmaf(e4.y, bf2f(hs[64 + lane]), acc[1]);
        acc[2] = fmaf(e4.z, bf2f(hs[128 + lane]), acc[2]);
        acc[3] = fmaf(e4.w, bf2f(hs[192 + lane]), acc[3]);
    }
    float z = 0.25f * (acc[0] / den[0] + acc[1] / den[1] +
                       acc[2] / den[2] + acc[3] / den[3]) + bias[lane];
    z = (z > 0.f) ? z : expm1f(z);
    zall[(size_t)d * 192 + mslice * 64 + lane] = z;
}

// ---------- semantic attention: sem_W column in VGPRs, z via LDS broadcast ----------
__global__ __launch_bounds__(256) void k_semantic(const float* __restrict__ zall,
                                                  const float* __restrict__ semW,
                                                  const float* __restrict__ semb,
                                                  const float* __restrict__ avec,
                                                  float* __restrict__ out) {
    __shared__ float zbuf[4][192];
    int t = threadIdx.x;
    int lane = t & 63;
    int wid = t >> 6;
    float wsc[64];
    #pragma unroll
    for (int k = 0; k < 64; ++k) wsc[k] = semW[k * 64 + lane];
    float sb = semb[lane];
    float av = avec[lane];
    int gw = blockIdx.x * 4 + wid;
    int nwv = gridDim.x * 4;
    for (int n = gw; n < NN; n += nwv) {
        float zm0 = zall[(size_t)n * 192 + lane];
        float zm1 = zall[(size_t)n * 192 + 64 + lane];
        float zm2 = zall[(size_t)n * 192 + 128 + lane];
        zbuf[wid][lane] = zm0;
        zbuf[wid][64 + lane] = zm1;
        zbuf[wid][128 + lane] = zm2;
        float sc3[3];
        #pragma unroll
        for (int m = 0; m < 3; ++m) {
            float a0 = sb, a1 = 0.f, a2 = 0.f, a3 = 0.f;
            #pragma unroll
            for (int k4 = 0; k4 < 16; ++k4) {
                float4 z4 = *(const float4*)&zbuf[wid][m * 64 + k4 * 4];
                a0 = fmaf(z4.x, wsc[k4 * 4 + 0], a0);
                a1 = fmaf(z4.y, wsc[k4 * 4 + 1], a1);
                a2 = fmaf(z4.z, wsc[k4 * 4 + 2], a2);
                a3 = fmaf(z4.w, wsc[k4 * 4 + 3], a3);
            }
            float wg = tanhf((a0 + a1) + (a2 + a3));
            float p = wg * av;
            #pragma unroll
            for (int o = 32; o > 0; o >>= 1) p += __shfl_xor(p, o);
            sc3[m] = p;
        }
        float mx = fmaxf(sc3[0], fmaxf(sc3[1], sc3[2]));
        float e0 = expf(sc3[0] - mx), e1 = expf(sc3[1] - mx), e2 = expf(sc3[2] - mx);
        float inv = 1.f / (e0 + e1 + e2);
        float b0 = e0 * inv, b1 = e1 * inv, b2 = e2 * inv;
        out[(size_t)n * 64 + lane] = b0 * zm0 + b1 * zm1 + b2 * zm2;
        if (lane < 3) {
            float b = (lane == 0) ? b0 : (lane == 1) ? b1 : b2;
            out[(size_t)NN * 64 + (size_t)n * 3 + lane] = b;
        }
    }
}

// ---------- host ----------
extern "C" void kernel_launch(void* const* d_in, const int* in_sizes, int n_in,
                              void* d_out, int out_size, void* d_ws, size_t ws_size,
                              hipStream_t stream) {
    (void)in_sizes; (void)n_in; (void)out_size; (void)ws_size;
    const float* x        = (const float*)d_in[0];
    const int*   ei       = (const int*)d_in[1];
    const float* eattr    = (const float*)d_in[2];
    const float* W        = (const float*)d_in[3];
    const float* att_src  = (const float*)d_in[4];
    const float* att_dst  = (const float*)d_in[5];
    const float* lin_edge = (const float*)d_in[6];
    const float* att_edge = (const float*)d_in[7];
    const float* bias     = (const float*)d_in[8];
    const float* bn_gamma = (const float*)d_in[9];
    const float* bn_beta  = (const float*)d_in[10];
    const float* sem_W    = (const float*)d_in[11];
    const float* sem_b    = (const float*)d_in[12];
    const float* attn_vec = (const float*)d_in[13];
    float* out = (float*)d_out;

    float* ws = (float*)d_ws;
    size_t o = 0;
    unsigned short* hbf = (unsigned short*)(ws + o); o += (size_t)NN * 128;  // 25.6 MB (bf16)
    float* zall   = ws + o; o += (size_t)NN * 192;   // 38.4 MB
    float* cex    = ws + o; o += (size_t)NE * 4;     //  6.4 MB
    int*   csrc   = (int*)(ws + o); o += (size_t)NE; //  1.6 MB
    float* asn    = ws + o; o += (size_t)NN * 4;
    float* adn    = ws + o; o += (size_t)NN * 4;
    int*   deg3   = (int*)(ws + o); o += (size_t)NM * NN;
    float* asum3  = ws + o; o += (size_t)NM * NN;
    int*   ptr3   = (int*)(ws + o); o += (size_t)NM * (NN + 1);
    int*   cur3   = (int*)(ws + o); o += (size_t)NM * NN;
    float* scal3  = ws + o; o += NM * 16;
    // total ~77 MB

    k_init<<<((NM * NN) + 255) / 256, 256, 0, stream>>>(deg3, asum3, scal3);
    k_bn_reduce<<<dim3(256, NM), 256, 0, stream>>>(eattr, scal3);
    k_bn_fin<<<NM, 64, 0, stream>>>(bn_gamma, bn_beta, lin_edge, att_edge, scal3);
    k_edge_deg<<<dim3((NE + 255) / 256, NM), 256, 0, stream>>>(eattr, ei, scal3, deg3, asum3);
    k_scan<<<NM, 1024, 0, stream>>>(deg3, ptr3, cur3);

    for (int m = 0; m < NM; ++m) {
        const int* srcA = ei + (size_t)m * 2 * NE;
        const int* dstA = srcA + NE;
        const float* eam = eattr + (size_t)m * NE;

        k_gemm<<<dim3((NN + 63) / 64, NH), 256, 0, stream>>>(
            x, W + (size_t)m * IND * HO,
            att_src + (size_t)m * HO, att_dst + (size_t)m * HO,
            hbf, asn, adn);
        k_scatter<<<(NE + 255) / 256, 256, 0, stream>>>(
            srcA, dstA, eam, scal3 + m * 16, asn, adn,
            cur3 + (size_t)m * NN, csrc, cex);
        k_passC<<<((size_t)NN * 64 + 255) / 256, 256, 0, stream>>>(
            ptr3 + (size_t)m * (NN + 1), csrc, cex, hbf, asn, adn,
            deg3 + (size_t)m * NN, asum3 + (size_t)m * NN,
            scal3 + m * 16, bias + (size_t)m * 64, zall, m);
    }

    k_semantic<<<2048, 256, 0, stream>>>(zall, sem_W, sem_b, attn_vec, out);
}